// Round 7
// baseline (258.597 us; speedup 1.0000x reference)
//
#include <hip/hip_runtime.h>

typedef short s16x8 __attribute__((ext_vector_type(8)));
typedef float f32x4 __attribute__((ext_vector_type(4)));
typedef unsigned short us;

__device__ inline us f2bf(float f){
    union{float f;unsigned u;} v{f};
    unsigned r = v.u + 0x7fff + ((v.u>>16)&1);
    return (us)(r>>16);
}

__device__ __forceinline__ void glds16(const us* g, us* l){
    __builtin_amdgcn_global_load_lds(
        (const __attribute__((address_space(1))) unsigned int*)(g),
        (__attribute__((address_space(3))) unsigned int*)(l), 16, 0, 0);
}
__device__ __forceinline__ void glds16f(const float* g, float* l){
    __builtin_amdgcn_global_load_lds(
        (const __attribute__((address_space(1))) unsigned int*)(g),
        (__attribute__((address_space(3))) unsigned int*)(l), 16, 0, 0);
}

// cvt 8 f32 -> s16x8 bf16 (RNE), via packed cvt (4 VALU, not 24 scalar ops)
__device__ __forceinline__ s16x8 cvt8(const float4 lo, const float4 hi){
    union{unsigned u[4]; s16x8 v;} o;
    asm("v_cvt_pk_bf16_f32 %0, %1, %2" : "=v"(o.u[0]) : "v"(lo.x), "v"(lo.y));
    asm("v_cvt_pk_bf16_f32 %0, %1, %2" : "=v"(o.u[1]) : "v"(lo.z), "v"(lo.w));
    asm("v_cvt_pk_bf16_f32 %0, %1, %2" : "=v"(o.u[2]) : "v"(hi.x), "v"(hi.y));
    asm("v_cvt_pk_bf16_f32 %0, %1, %2" : "=v"(o.u[3]) : "v"(hi.z), "v"(hi.w));
    return o.v;
}

// ---------------- cast weights only (x cast is fused into gemm_qkv) ----------------
__global__ void cast_w(const float* __restrict__ wqkv_w, const float* __restrict__ wp_w,
                       us* __restrict__ wqkvbf, us* __restrict__ wpbf){
    int i = blockIdx.x*blockDim.x + threadIdx.x;   // 262144 float4s
    const float* s; us* d; int j;
    if(i < 196608){ s = wqkv_w; d = wqkvbf; j = i; }
    else { s = wp_w; d = wpbf; j = i - 196608; }
    float4 f = ((const float4*)s)[j];
    ushort4 o;
    o.x = f2bf(f.x); o.y = f2bf(f.y); o.z = f2bf(f.z); o.w = f2bf(f.w);
    ((ushort4*)d)[j] = o;
}

// ==== qkv = x @ wqkv^T + b (M=32768,N=1536,K=512), x read in f32 DIRECTLY ====
// A staged f32 via glds16 (32KB), 16B-slot XOR swizzle slot^=2*(row&7);
// frag read = 2x float4 + v_cvt_pk_bf16_f32. B staged bf16 as before (16KB).
// LDS 48KB -> 3 blocks/CU. Swapped-operand MFMA + ushort4 epilogue (verified).
__launch_bounds__(256,3)
__global__ void gemm_qkv(const float* __restrict__ X, const us* __restrict__ B,
                         const float* __restrict__ bias, us* __restrict__ C){
    __shared__ __attribute__((aligned(16))) float sAf[128*64];
    __shared__ __attribute__((aligned(16))) us sB[128*64];
    int t = threadIdx.x;
    int id = blockIdx.x;                 // 3072
    int xcd = id & 7, s = id >> 3;
    int nt = s % 12, mt = xcd*32 + s/12;
    int lane = t&63, wave = t>>6, quad = lane>>4, l15 = lane&15;
    int wm = wave>>1, wn = wave&1;

    int l16r = lane>>4;                  // row-within-4 for A staging (4 rows/glds16)
    int sl = lane&15;                    // 16B slot within 256B row
    // A source: lane covers row (base+l16r), LDS slot sl holds global slot
    // sl ^ 2*(rowg&7); rowg&7 = 4*(round&1) + l16r  ->  ^8 for odd rounds.
    int swzA = (sl ^ (2*l16r)) << 2;     // float offset, even rounds
    const float* Ae = X + (size_t)(mt*128 + wave*32 + l16r)*512 + swzA;
    const float* Ao = X + (size_t)(mt*128 + wave*32 + l16r)*512 + (swzA ^ 32);
    int l8 = lane>>3;
    int swB = ((lane&7) ^ l8)*8;
    const us* Bg = B + (size_t)(nt*128 + wave*32 + l8)*512 + swB;
    float* sAw = &sAf[(wave*32)*64];
    us*    sBw = &sB[(wave*32)*64];

    f32x4 acc[4][4];
    #pragma unroll
    for(int i=0;i<4;i++)
        #pragma unroll
        for(int j=0;j<4;j++) acc[i][j] = (f32x4){0.f,0.f,0.f,0.f};

    for(int k0=0; k0<512; k0+=64){
        #pragma unroll
        for(int r=0;r<8;r++){
            const float* src = (r&1) ? Ao : Ae;
            glds16f(src + (size_t)r*4*512 + k0, sAw + r*4*64);
        }
        glds16(Bg + k0,           sBw);
        glds16(Bg + 8*512 + k0,   sBw + 8*64);
        glds16(Bg + 16*512 + k0,  sBw + 16*64);
        glds16(Bg + 24*512 + k0,  sBw + 24*64);
        __syncthreads();
        #pragma unroll
        for(int ks=0; ks<2; ks++){
            int kc = ks*4 + quad;
            s16x8 af[4], bfr[4];
            #pragma unroll
            for(int i=0;i<4;i++){
                int r = wm*64 + i*16 + l15;
                const float* p = &sAf[r*64 + ((kc ^ (r&7))<<3)];
                af[i] = cvt8(*(const float4*)p, *(const float4*)(p+4));
            }
            #pragma unroll
            for(int j=0;j<4;j++){
                int r = wn*64 + j*16 + l15;
                bfr[j] = *(const s16x8*)&sB[r*64 + ((kc ^ (r&7))<<3)];
            }
            #pragma unroll
            for(int i=0;i<4;i++)
                #pragma unroll
                for(int j=0;j<4;j++)
                    acc[i][j] = __builtin_amdgcn_mfma_f32_16x16x32_bf16(bfr[j], af[i], acc[i][j], 0,0,0);
        }
        __syncthreads();
    }

    // swapped layout: lane holds row = row0+i*16+l15, cols = col0+j*16+quad*4..+3
    int row0 = mt*128 + wm*64, col0 = nt*128 + wn*64;
    float4 bv[4];
    #pragma unroll
    for(int j=0;j<4;j++) bv[j] = *(const float4*)&bias[col0 + j*16 + quad*4];
    #pragma unroll
    for(int i=0;i<4;i++){
        size_t rb = (size_t)(row0 + i*16 + l15)*1536 + col0;
        #pragma unroll
        for(int j=0;j<4;j++){
            ushort4 o;
            o.x = f2bf(acc[i][j][0] + bv[j].x);
            o.y = f2bf(acc[i][j][1] + bv[j].y);
            o.z = f2bf(acc[i][j][2] + bv[j].z);
            o.w = f2bf(acc[i][j][3] + bv[j].w);
            *(ushort4*)&C[rb + j*16 + quad*4] = o;
        }
    }
}

// ---- scores: Spart[kb][head][d][e] = partial over 512 tokens (kb<8, 8 chunks) ----
__launch_bounds__(256,4)
__global__ void attn_scores_mfma(const us* __restrict__ qkv, float* __restrict__ Sp){
    __shared__ __attribute__((aligned(16))) us sQt[64*72];
    __shared__ __attribute__((aligned(16))) us sKt[64*72];
    int t = threadIdx.x;
    int kb = blockIdx.x, head = blockIdx.y;   // kb < 8
    int lane = t & 63, w = t >> 6;
    int quad = lane >> 4, l15 = lane & 15;
    int p = t & 31;
    int d0 = (t >> 5) * 8;

    f32x4 acc[4];
    #pragma unroll
    for(int j=0;j<4;j++) acc[j] = (f32x4){0.f,0.f,0.f,0.f};

    for(int chunk=0; chunk<8; chunk++){
        int r0 = head*512 + kb*64 + chunk*8;
        const us* g = qkv + (size_t)(r0 + (p>>2))*1536 + (2*(p&3))*64 + d0;
        union{uint4 v; us h[8];} q0, q1, k0, k1;
        q0.v = *(const uint4*)g;         q1.v = *(const uint4*)(g + 64);
        k0.v = *(const uint4*)(g + 512); k1.v = *(const uint4*)(g + 576);
        #pragma unroll
        for(int j=0;j<8;j++){
            *(unsigned*)&sQt[(d0+j)*72 + 2*p] = (unsigned)q0.h[j] | ((unsigned)q1.h[j]<<16);
            *(unsigned*)&sKt[(d0+j)*72 + 2*p] = (unsigned)k0.h[j] | ((unsigned)k1.h[j]<<16);
        }
        __syncthreads();
        int d = w*16 + l15;
        #pragma unroll
        for(int ks=0; ks<2; ks++){
            int tb = ks*4 + quad;
            s16x8 af = *(const s16x8*)&sQt[d*72 + tb*8];
            #pragma unroll
            for(int jt=0; jt<4; jt++){
                int e = jt*16 + l15;
                s16x8 bfv = *(const s16x8*)&sKt[e*72 + tb*8];
                acc[jt] = __builtin_amdgcn_mfma_f32_16x16x32_bf16(af, bfv, acc[jt], 0,0,0);
            }
        }
        __syncthreads();
    }

    float* S = Sp + (size_t)(kb*64 + head)*4096;
    #pragma unroll
    for(int jt=0; jt<4; jt++){
        int e = jt*16 + l15;
        #pragma unroll
        for(int r=0; r<4; r++){
            int d = w*16 + quad*4 + r;
            S[d*64 + e] = acc[jt][r];
        }
    }
}

// ---- fused softmax+fold (verified r4): 256 blocks (head,part). Each block
// computes its head's full 64x64 softmax straight into LDS, then fold quarter. ----
__launch_bounds__(256,2)
__global__ void softfold(const float* __restrict__ Sp, const us* __restrict__ wpbf,
                         us* __restrict__ Mcat){
    __shared__ us sWt[64*72];   // W^T: sWt[e][d]
    int t = threadIdx.x;
    int head = blockIdx.x>>2, part = blockIdx.x&3;
    int b = head>>3, h = head&7;
    int lane = t&63, w = t>>6, quad = lane>>4, l15 = lane&15;

    int d = t>>2, e0 = (t&3)*16;
    float vv[16];
    #pragma unroll
    for(int j=0;j<16;j++) vv[j] = 0.f;
    for(int kb=0; kb<8; kb++){
        const float4* pp = (const float4*)&Sp[(size_t)(kb*64 + head)*4096 + d*64 + e0];
        #pragma unroll
        for(int q=0;q<4;q++){
            float4 g = pp[q];
            vv[4*q+0]+=g.x; vv[4*q+1]+=g.y; vv[4*q+2]+=g.z; vv[4*q+3]+=g.w;
        }
    }
    float m = -1e30f;
    #pragma unroll
    for(int j=0;j<16;j++){ vv[j] *= 0.125f; m = fmaxf(m, vv[j]); }
    m = fmaxf(m, __shfl_xor(m, 1));
    m = fmaxf(m, __shfl_xor(m, 2));
    float ssum = 0.f;
    #pragma unroll
    for(int j=0;j<16;j++){ vv[j] = __expf(vv[j]-m); ssum += vv[j]; }
    ssum += __shfl_xor(ssum, 1);
    ssum += __shfl_xor(ssum, 2);
    float inv = 1.f/ssum;
    #pragma unroll
    for(int j=0;j<16;j++) sWt[(e0+j)*72 + d] = f2bf(vv[j]*inv);
    __syncthreads();

    #pragma unroll
    for(int i=0;i<2;i++){
        int nO = part*128 + w*32 + i*16 + l15;
        s16x8 af0 = *(const s16x8*)&wpbf[(size_t)nO*512 + h*64 + quad*8];
        s16x8 af1 = *(const s16x8*)&wpbf[(size_t)nO*512 + h*64 + 32 + quad*8];
        #pragma unroll
        for(int j=0;j<4;j++){
            s16x8 bf0 = *(const s16x8*)&sWt[(j*16+l15)*72 + quad*8];
            s16x8 bf1 = *(const s16x8*)&sWt[(j*16+l15)*72 + 32 + quad*8];
            f32x4 acc = (f32x4){0.f,0.f,0.f,0.f};
            acc = __builtin_amdgcn_mfma_f32_16x16x32_bf16(af0, bf0, acc, 0,0,0);
            acc = __builtin_amdgcn_mfma_f32_16x16x32_bf16(af1, bf1, acc, 0,0,0);
            #pragma unroll
            for(int r=0;r<4;r++){
                int row = part*128 + w*32 + i*16 + quad*4 + r;
                Mcat[((size_t)(b*512 + row))*512 + h*64 + j*16 + l15] = f2bf(acc[r]);
            }
        }
    }
}

// ---- out_b = Vgather_b @ Mcat_b^T + wp_b. Swapped MFMA + float4 stores
// (verified r4/r5). ----
__launch_bounds__(256,4)
__global__ void gemm_vout(const us* __restrict__ qkv, const us* __restrict__ Mcat,
                          const float* __restrict__ bias, float* __restrict__ out){
    __shared__ __attribute__((aligned(16))) us sA[128*64];
    __shared__ __attribute__((aligned(16))) us sB[128*64];
    int t = threadIdx.x;
    int id = blockIdx.x;                 // 1024
    int xcd = id & 7, s = id >> 3;
    int nt = s & 3, mt = xcd*32 + (s>>2);
    int b = mt>>5, mr = mt&31;
    int lane = t&63, wave = t>>6, quad = lane>>4, l15 = lane&15;
    int wm = wave>>1, wn = wave&1;

    int l8 = lane>>3;
    int sw = ((lane&7) ^ l8)*8;
    const us* Abase = qkv + ((size_t)(8*b)*512 + mr*16 + wave*4)*1536 + 1024 + l8*64 + sw;
    const us* Bbase = Mcat + ((size_t)(b*512 + nt*128 + wave*32 + l8))*512 + sw;
    us* sAw = &sA[(wave*32)*64];
    us* sBw = &sB[(wave*32)*64];

    f32x4 acc[4][4];
    #pragma unroll
    for(int i=0;i<4;i++)
        #pragma unroll
        for(int j=0;j<4;j++) acc[i][j] = (f32x4){0.f,0.f,0.f,0.f};

    for(int h=0; h<8; h++){
        const us* Ah = Abase + (size_t)h*512*1536;
        const us* Bh = Bbase + h*64;
        glds16(Ah,           sAw);
        glds16(Ah + 1536,    sAw + 8*64);
        glds16(Ah + 2*1536,  sAw + 16*64);
        glds16(Ah + 3*1536,  sAw + 24*64);
        glds16(Bh,           sBw);
        glds16(Bh + 8*512,   sBw + 8*64);
        glds16(Bh + 16*512,  sBw + 16*64);
        glds16(Bh + 24*512,  sBw + 24*64);
        __syncthreads();
        #pragma unroll
        for(int ks=0; ks<2; ks++){
            int kc = ks*4 + quad;
            s16x8 af[4], bfr[4];
            #pragma unroll
            for(int i=0;i<4;i++){
                int r = wm*64 + i*16 + l15;
                af[i] = *(const s16x8*)&sA[r*64 + ((kc ^ (r&7))<<3)];
            }
            #pragma unroll
            for(int j=0;j<4;j++){
                int r = wn*64 + j*16 + l15;
                bfr[j] = *(const s16x8*)&sB[r*64 + ((kc ^ (r&7))<<3)];
            }
            #pragma unroll
            for(int i=0;i<4;i++)
                #pragma unroll
                for(int j=0;j<4;j++)
                    acc[i][j] = __builtin_amdgcn_mfma_f32_16x16x32_bf16(bfr[j], af[i], acc[i][j], 0,0,0);
        }
        __syncthreads();
    }

    int row0 = b*4096 + mr*128 + wm*64;
    int col0 = nt*128 + wn*64;
    float4 bv[4];
    #pragma unroll
    for(int j=0;j<4;j++) bv[j] = *(const float4*)&bias[col0 + j*16 + quad*4];
    #pragma unroll
    for(int i=0;i<4;i++){
        size_t rb = (size_t)(row0 + i*16 + l15)*512 + col0;
        #pragma unroll
        for(int j=0;j<4;j++){
            float4 o;
            o.x = acc[i][j][0] + bv[j].x;
            o.y = acc[i][j][1] + bv[j].y;
            o.z = acc[i][j][2] + bv[j].z;
            o.w = acc[i][j][3] + bv[j].w;
            *(float4*)&out[rb + j*16 + quad*4] = o;
        }
    }
}

extern "C" void kernel_launch(void* const* d_in, const int* in_sizes, int n_in,
                              void* d_out, int out_size, void* d_ws, size_t ws_size,
                              hipStream_t stream){
    const float* x      = (const float*)d_in[0];
    const float* wqkv_w = (const float*)d_in[1];
    const float* wqkv_b = (const float*)d_in[2];
    const float* wp_w   = (const float*)d_in[3];
    const float* wp_b   = (const float*)d_in[4];

    char* ws = (char*)d_ws;
    us*    qkvbf  = (us*)(ws);                    // 96 MB
    float* Spart  = (float*)(ws + 134217728);     // 8 MB
    us*    Mcat   = (us*)(ws + 143130624);        // 4 MB
    us*    wqkvbf = (us*)(ws + 147324928);        // 1.5 MB
    us*    wpbf   = (us*)(ws + 148897792);        // 0.5 MB

    cast_w<<<1024,256,0,stream>>>(wqkv_w, wp_w, wqkvbf, wpbf);

    gemm_qkv<<<3072,256,0,stream>>>(x, wqkvbf, wqkv_b, qkvbf);

    attn_scores_mfma<<<dim3(8,64),256,0,stream>>>(qkvbf, Spart);
    softfold<<<256,256,0,stream>>>(Spart, wpbf, Mcat);

    gemm_vout<<<1024,256,0,stream>>>(qkvbf, Mcat, wp_b, (float*)d_out);
}

// Round 8
// 258.103 us; speedup vs baseline: 1.0019x; 1.0019x over previous
//
#include <hip/hip_runtime.h>

typedef short s16x8 __attribute__((ext_vector_type(8)));
typedef float f32x4 __attribute__((ext_vector_type(4)));
typedef unsigned short us;

__device__ inline us f2bf(float f){
    union{float f;unsigned u;} v{f};
    unsigned r = v.u + 0x7fff + ((v.u>>16)&1);
    return (us)(r>>16);
}

__device__ __forceinline__ void glds16(const us* g, us* l){
    __builtin_amdgcn_global_load_lds(
        (const __attribute__((address_space(1))) unsigned int*)(g),
        (__attribute__((address_space(3))) unsigned int*)(l), 16, 0, 0);
}
__device__ __forceinline__ void glds16f(const float* g, float* l){
    __builtin_amdgcn_global_load_lds(
        (const __attribute__((address_space(1))) unsigned int*)(g),
        (__attribute__((address_space(3))) unsigned int*)(l), 16, 0, 0);
}

// cvt 8 f32 -> s16x8 bf16 (RNE), via packed cvt (4 VALU, not 24 scalar ops)
__device__ __forceinline__ s16x8 cvt8(const float4 lo, const float4 hi){
    union{unsigned u[4]; s16x8 v;} o;
    asm("v_cvt_pk_bf16_f32 %0, %1, %2" : "=v"(o.u[0]) : "v"(lo.x), "v"(lo.y));
    asm("v_cvt_pk_bf16_f32 %0, %1, %2" : "=v"(o.u[1]) : "v"(lo.z), "v"(lo.w));
    asm("v_cvt_pk_bf16_f32 %0, %1, %2" : "=v"(o.u[2]) : "v"(hi.x), "v"(hi.y));
    asm("v_cvt_pk_bf16_f32 %0, %1, %2" : "=v"(o.u[3]) : "v"(hi.z), "v"(hi.w));
    return o.v;
}

// ---------------- cast weights only (x cast is fused into gemm_qkv) ----------------
__global__ void cast_w(const float* __restrict__ wqkv_w, const float* __restrict__ wp_w,
                       us* __restrict__ wqkvbf, us* __restrict__ wpbf){
    int i = blockIdx.x*blockDim.x + threadIdx.x;   // 262144 float4s
    const float* s; us* d; int j;
    if(i < 196608){ s = wqkv_w; d = wqkvbf; j = i; }
    else { s = wp_w; d = wpbf; j = i - 196608; }
    float4 f = ((const float4*)s)[j];
    ushort4 o;
    o.x = f2bf(f.x); o.y = f2bf(f.y); o.z = f2bf(f.z); o.w = f2bf(f.w);
    ((ushort4*)d)[j] = o;
}

// ==== qkv = x @ wqkv^T + b (M=32768,N=1536,K=512), x read in f32 DIRECTLY ====
// A staged f32 via glds16 (32KB), FULL-granular 16B-slot swizzle:
//   LDS slot = global slot ^ (row&7)   (odd+even key -> all 8 bank-quads)
// Frag read = TWO independent ds_read_b128 at base and base^4 (slots (2kc)^key,
// (2kc+1)^key differ only in bit0), then v_cvt_pk_bf16_f32. r7's even-only key
// 2*(kc^(r&7)) hit {0,2,4,6} quads = 4-way conflict (6.3M measured); this key
// spans all 8 -> 2 lanes/quad = free. B staged bf16 as before (16KB).
// LDS 48KB -> 3 blocks/CU. Swapped-operand MFMA + ushort4 epilogue (verified).
__launch_bounds__(256,3)
__global__ void gemm_qkv(const float* __restrict__ X, const us* __restrict__ B,
                         const float* __restrict__ bias, us* __restrict__ C){
    __shared__ __attribute__((aligned(16))) float sAf[128*64];
    __shared__ __attribute__((aligned(16))) us sB[128*64];
    int t = threadIdx.x;
    int id = blockIdx.x;                 // 3072
    int xcd = id & 7, s = id >> 3;
    int nt = s % 12, mt = xcd*32 + s/12;
    int lane = t&63, wave = t>>6, quad = lane>>4, l15 = lane&15;
    int wm = wave>>1, wn = wave&1;

    int l16r = lane>>4;                  // row-within-4 for A staging (4 rows/glds16)
    int sl = lane&15;                    // 16B slot within 256B row window
    // staging round r covers rows r*4+l16r; row&7 = 4*(r&1)+l16r.
    // even rounds: key = l16r ; odd rounds: key = l16r^4 (slot^4 = float ^16)
    int swzE = (sl ^ l16r) << 2;         // float offset of swizzled slot, even rounds
    const float* Ae = X + (size_t)(mt*128 + wave*32 + l16r)*512 + swzE;
    const float* Ao = X + (size_t)(mt*128 + wave*32 + l16r)*512 + (swzE ^ 16);
    int l8 = lane>>3;
    int swB = ((lane&7) ^ l8)*8;
    const us* Bg = B + (size_t)(nt*128 + wave*32 + l8)*512 + swB;
    float* sAw = &sAf[(wave*32)*64];
    us*    sBw = &sB[(wave*32)*64];

    f32x4 acc[4][4];
    #pragma unroll
    for(int i=0;i<4;i++)
        #pragma unroll
        for(int j=0;j<4;j++) acc[i][j] = (f32x4){0.f,0.f,0.f,0.f};

    for(int k0=0; k0<512; k0+=64){
        #pragma unroll
        for(int r=0;r<8;r++){
            const float* src = (r&1) ? Ao : Ae;
            glds16f(src + (size_t)r*4*512 + k0, sAw + r*4*64);
        }
        glds16(Bg + k0,           sBw);
        glds16(Bg + 8*512 + k0,   sBw + 8*64);
        glds16(Bg + 16*512 + k0,  sBw + 16*64);
        glds16(Bg + 24*512 + k0,  sBw + 24*64);
        __syncthreads();
        #pragma unroll
        for(int ks=0; ks<2; ks++){
            int kc = ks*4 + quad;
            s16x8 af[4], bfr[4];
            #pragma unroll
            for(int i=0;i<4;i++){
                int r = wm*64 + i*16 + l15;
                int base = r*64 + (((2*kc) ^ (r&7))<<2);   // LDS addr of global slot 2kc
                af[i] = cvt8(*(const float4*)&sAf[base],   // slot 2kc   (swizzled)
                             *(const float4*)&sAf[base ^ 4]); // slot 2kc+1 (bit0 flip)
            }
            #pragma unroll
            for(int j=0;j<4;j++){
                int r = wn*64 + j*16 + l15;
                bfr[j] = *(const s16x8*)&sB[r*64 + ((kc ^ (r&7))<<3)];
            }
            #pragma unroll
            for(int i=0;i<4;i++)
                #pragma unroll
                for(int j=0;j<4;j++)
                    acc[i][j] = __builtin_amdgcn_mfma_f32_16x16x32_bf16(bfr[j], af[i], acc[i][j], 0,0,0);
        }
        __syncthreads();
    }

    // swapped layout: lane holds row = row0+i*16+l15, cols = col0+j*16+quad*4..+3
    int row0 = mt*128 + wm*64, col0 = nt*128 + wn*64;
    float4 bv[4];
    #pragma unroll
    for(int j=0;j<4;j++) bv[j] = *(const float4*)&bias[col0 + j*16 + quad*4];
    #pragma unroll
    for(int i=0;i<4;i++){
        size_t rb = (size_t)(row0 + i*16 + l15)*1536 + col0;
        #pragma unroll
        for(int j=0;j<4;j++){
            ushort4 o;
            o.x = f2bf(acc[i][j][0] + bv[j].x);
            o.y = f2bf(acc[i][j][1] + bv[j].y);
            o.z = f2bf(acc[i][j][2] + bv[j].z);
            o.w = f2bf(acc[i][j][3] + bv[j].w);
            *(ushort4*)&C[rb + j*16 + quad*4] = o;
        }
    }
}

// ---- scores: Spart[kb][head][d][e] = partial over 512 tokens (kb<8, 8 chunks) ----
__launch_bounds__(256,4)
__global__ void attn_scores_mfma(const us* __restrict__ qkv, float* __restrict__ Sp){
    __shared__ __attribute__((aligned(16))) us sQt[64*72];
    __shared__ __attribute__((aligned(16))) us sKt[64*72];
    int t = threadIdx.x;
    int kb = blockIdx.x, head = blockIdx.y;   // kb < 8
    int lane = t & 63, w = t >> 6;
    int quad = lane >> 4, l15 = lane & 15;
    int p = t & 31;
    int d0 = (t >> 5) * 8;

    f32x4 acc[4];
    #pragma unroll
    for(int j=0;j<4;j++) acc[j] = (f32x4){0.f,0.f,0.f,0.f};

    for(int chunk=0; chunk<8; chunk++){
        int r0 = head*512 + kb*64 + chunk*8;
        const us* g = qkv + (size_t)(r0 + (p>>2))*1536 + (2*(p&3))*64 + d0;
        union{uint4 v; us h[8];} q0, q1, k0, k1;
        q0.v = *(const uint4*)g;         q1.v = *(const uint4*)(g + 64);
        k0.v = *(const uint4*)(g + 512); k1.v = *(const uint4*)(g + 576);
        #pragma unroll
        for(int j=0;j<8;j++){
            *(unsigned*)&sQt[(d0+j)*72 + 2*p] = (unsigned)q0.h[j] | ((unsigned)q1.h[j]<<16);
            *(unsigned*)&sKt[(d0+j)*72 + 2*p] = (unsigned)k0.h[j] | ((unsigned)k1.h[j]<<16);
        }
        __syncthreads();
        int d = w*16 + l15;
        #pragma unroll
        for(int ks=0; ks<2; ks++){
            int tb = ks*4 + quad;
            s16x8 af = *(const s16x8*)&sQt[d*72 + tb*8];
            #pragma unroll
            for(int jt=0; jt<4; jt++){
                int e = jt*16 + l15;
                s16x8 bfv = *(const s16x8*)&sKt[e*72 + tb*8];
                acc[jt] = __builtin_amdgcn_mfma_f32_16x16x32_bf16(af, bfv, acc[jt], 0,0,0);
            }
        }
        __syncthreads();
    }

    float* S = Sp + (size_t)(kb*64 + head)*4096;
    #pragma unroll
    for(int jt=0; jt<4; jt++){
        int e = jt*16 + l15;
        #pragma unroll
        for(int r=0; r<4; r++){
            int d = w*16 + quad*4 + r;
            S[d*64 + e] = acc[jt][r];
        }
    }
}

// ---- fused softmax+fold (verified r4/r7): 256 blocks (head,part). Each block
// computes its head's full 64x64 softmax straight into LDS, then fold quarter. ----
__launch_bounds__(256,2)
__global__ void softfold(const float* __restrict__ Sp, const us* __restrict__ wpbf,
                         us* __restrict__ Mcat){
    __shared__ us sWt[64*72];   // W^T: sWt[e][d]
    int t = threadIdx.x;
    int head = blockIdx.x>>2, part = blockIdx.x&3;
    int b = head>>3, h = head&7;
    int lane = t&63, w = t>>6, quad = lane>>4, l15 = lane&15;

    int d = t>>2, e0 = (t&3)*16;
    float vv[16];
    #pragma unroll
    for(int j=0;j<16;j++) vv[j] = 0.f;
    for(int kb=0; kb<8; kb++){
        const float4* pp = (const float4*)&Sp[(size_t)(kb*64 + head)*4096 + d*64 + e0];
        #pragma unroll
        for(int q=0;q<4;q++){
            float4 g = pp[q];
            vv[4*q+0]+=g.x; vv[4*q+1]+=g.y; vv[4*q+2]+=g.z; vv[4*q+3]+=g.w;
        }
    }
    float m = -1e30f;
    #pragma unroll
    for(int j=0;j<16;j++){ vv[j] *= 0.125f; m = fmaxf(m, vv[j]); }
    m = fmaxf(m, __shfl_xor(m, 1));
    m = fmaxf(m, __shfl_xor(m, 2));
    float ssum = 0.f;
    #pragma unroll
    for(int j=0;j<16;j++){ vv[j] = __expf(vv[j]-m); ssum += vv[j]; }
    ssum += __shfl_xor(ssum, 1);
    ssum += __shfl_xor(ssum, 2);
    float inv = 1.f/ssum;
    #pragma unroll
    for(int j=0;j<16;j++) sWt[(e0+j)*72 + d] = f2bf(vv[j]*inv);
    __syncthreads();

    #pragma unroll
    for(int i=0;i<2;i++){
        int nO = part*128 + w*32 + i*16 + l15;
        s16x8 af0 = *(const s16x8*)&wpbf[(size_t)nO*512 + h*64 + quad*8];
        s16x8 af1 = *(const s16x8*)&wpbf[(size_t)nO*512 + h*64 + 32 + quad*8];
        #pragma unroll
        for(int j=0;j<4;j++){
            s16x8 bf0 = *(const s16x8*)&sWt[(j*16+l15)*72 + quad*8];
            s16x8 bf1 = *(const s16x8*)&sWt[(j*16+l15)*72 + 32 + quad*8];
            f32x4 acc = (f32x4){0.f,0.f,0.f,0.f};
            acc = __builtin_amdgcn_mfma_f32_16x16x32_bf16(af0, bf0, acc, 0,0,0);
            acc = __builtin_amdgcn_mfma_f32_16x16x32_bf16(af1, bf1, acc, 0,0,0);
            #pragma unroll
            for(int r=0;r<4;r++){
                int row = part*128 + w*32 + i*16 + quad*4 + r;
                Mcat[((size_t)(b*512 + row))*512 + h*64 + j*16 + l15] = f2bf(acc[r]);
            }
        }
    }
}

// ---- out_b = Vgather_b @ Mcat_b^T + wp_b. Swapped MFMA + float4 stores
// (verified r4/r5). ----
__launch_bounds__(256,4)
__global__ void gemm_vout(const us* __restrict__ qkv, const us* __restrict__ Mcat,
                          const float* __restrict__ bias, float* __restrict__ out){
    __shared__ __attribute__((aligned(16))) us sA[128*64];
    __shared__ __attribute__((aligned(16))) us sB[128*64];
    int t = threadIdx.x;
    int id = blockIdx.x;                 // 1024
    int xcd = id & 7, s = id >> 3;
    int nt = s & 3, mt = xcd*32 + (s>>2);
    int b = mt>>5, mr = mt&31;
    int lane = t&63, wave = t>>6, quad = lane>>4, l15 = lane&15;
    int wm = wave>>1, wn = wave&1;

    int l8 = lane>>3;
    int sw = ((lane&7) ^ l8)*8;
    const us* Abase = qkv + ((size_t)(8*b)*512 + mr*16 + wave*4)*1536 + 1024 + l8*64 + sw;
    const us* Bbase = Mcat + ((size_t)(b*512 + nt*128 + wave*32 + l8))*512 + sw;
    us* sAw = &sA[(wave*32)*64];
    us* sBw = &sB[(wave*32)*64];

    f32x4 acc[4][4];
    #pragma unroll
    for(int i=0;i<4;i++)
        #pragma unroll
        for(int j=0;j<4;j++) acc[i][j] = (f32x4){0.f,0.f,0.f,0.f};

    for(int h=0; h<8; h++){
        const us* Ah = Abase + (size_t)h*512*1536;
        const us* Bh = Bbase + h*64;
        glds16(Ah,           sAw);
        glds16(Ah + 1536,    sAw + 8*64);
        glds16(Ah + 2*1536,  sAw + 16*64);
        glds16(Ah + 3*1536,  sAw + 24*64);
        glds16(Bh,           sBw);
        glds16(Bh + 8*512,   sBw + 8*64);
        glds16(Bh + 16*512,  sBw + 16*64);
        glds16(Bh + 24*512,  sBw + 24*64);
        __syncthreads();
        #pragma unroll
        for(int ks=0; ks<2; ks++){
            int kc = ks*4 + quad;
            s16x8 af[4], bfr[4];
            #pragma unroll
            for(int i=0;i<4;i++){
                int r = wm*64 + i*16 + l15;
                af[i] = *(const s16x8*)&sA[r*64 + ((kc ^ (r&7))<<3)];
            }
            #pragma unroll
            for(int j=0;j<4;j++){
                int r = wn*64 + j*16 + l15;
                bfr[j] = *(const s16x8*)&sB[r*64 + ((kc ^ (r&7))<<3)];
            }
            #pragma unroll
            for(int i=0;i<4;i++)
                #pragma unroll
                for(int j=0;j<4;j++)
                    acc[i][j] = __builtin_amdgcn_mfma_f32_16x16x32_bf16(bfr[j], af[i], acc[i][j], 0,0,0);
        }
        __syncthreads();
    }

    int row0 = b*4096 + mr*128 + wm*64;
    int col0 = nt*128 + wn*64;
    float4 bv[4];
    #pragma unroll
    for(int j=0;j<4;j++) bv[j] = *(const float4*)&bias[col0 + j*16 + quad*4];
    #pragma unroll
    for(int i=0;i<4;i++){
        size_t rb = (size_t)(row0 + i*16 + l15)*512 + col0;
        #pragma unroll
        for(int j=0;j<4;j++){
            float4 o;
            o.x = acc[i][j][0] + bv[j].x;
            o.y = acc[i][j][1] + bv[j].y;
            o.z = acc[i][j][2] + bv[j].z;
            o.w = acc[i][j][3] + bv[j].w;
            *(float4*)&out[rb + j*16 + quad*4] = o;
        }
    }
}

extern "C" void kernel_launch(void* const* d_in, const int* in_sizes, int n_in,
                              void* d_out, int out_size, void* d_ws, size_t ws_size,
                              hipStream_t stream){
    const float* x      = (const float*)d_in[0];
    const float* wqkv_w = (const float*)d_in[1];
    const float* wqkv_b = (const float*)d_in[2];
    const float* wp_w   = (const float*)d_in[3];
    const float* wp_b   = (const float*)d_in[4];

    char* ws = (char*)d_ws;
    us*    qkvbf  = (us*)(ws);                    // 96 MB
    float* Spart  = (float*)(ws + 134217728);     // 8 MB
    us*    Mcat   = (us*)(ws + 143130624);        // 4 MB
    us*    wqkvbf = (us*)(ws + 147324928);        // 1.5 MB
    us*    wpbf   = (us*)(ws + 148897792);        // 0.5 MB

    cast_w<<<1024,256,0,stream>>>(wqkv_w, wp_w, wqkvbf, wpbf);

    gemm_qkv<<<3072,256,0,stream>>>(x, wqkvbf, wqkv_b, qkvbf);

    attn_scores_mfma<<<dim3(8,64),256,0,stream>>>(qkvbf, Spart);
    softfold<<<256,256,0,stream>>>(Spart, wpbf, Mcat);

    gemm_vout<<<1024,256,0,stream>>>(qkvbf, Mcat, wp_b, (float*)d_out);
}

// Round 9
// 255.844 us; speedup vs baseline: 1.0108x; 1.0088x over previous
//
#include <hip/hip_runtime.h>

typedef short s16x8 __attribute__((ext_vector_type(8)));
typedef float f32x4 __attribute__((ext_vector_type(4)));
typedef unsigned short us;

__device__ inline us f2bf(float f){
    union{float f;unsigned u;} v{f};
    unsigned r = v.u + 0x7fff + ((v.u>>16)&1);
    return (us)(r>>16);
}

__device__ __forceinline__ void glds16(const us* g, us* l){
    __builtin_amdgcn_global_load_lds(
        (const __attribute__((address_space(1))) unsigned int*)(g),
        (__attribute__((address_space(3))) unsigned int*)(l), 16, 0, 0);
}

// ---------------- fused cast: x, wqkv_w, wp_w -> bf16, one launch ----------------
__global__ void cast_all(const float* __restrict__ x, const float* __restrict__ wqkv_w,
                         const float* __restrict__ wp_w, us* __restrict__ xbf,
                         us* __restrict__ wqkvbf, us* __restrict__ wpbf){
    int i = blockIdx.x*blockDim.x + threadIdx.x;   // 4456448 float4s
    const float* s; us* d; int j;
    if(i < 4194304){ s = x; d = xbf; j = i; }
    else if(i < 4390912){ s = wqkv_w; d = wqkvbf; j = i - 4194304; }
    else { s = wp_w; d = wpbf; j = i - 4390912; }
    float4 f = ((const float4*)s)[j];
    ushort4 o;
    o.x = f2bf(f.x); o.y = f2bf(f.y); o.z = f2bf(f.z); o.w = f2bf(f.w);
    ((ushort4*)d)[j] = o;
}

// ---- qkv = xbf @ wqkv^T + b  (M=32768,N=1536,K=512). r6 verified structure
// (bf16 LDS, 0 conflicts, 4 blocks/CU) + T3-minimal reorder: stage(k+1) issued
// AFTER barrier (b) (all reads done) and BEFORE the ks1 MFMA batch, so the DMA
// overlaps the MFMAs instead of draining raw at the next barrier. Single 32KB
// buffer, barrier count unchanged, per-ks frag liveness unchanged. ----
__launch_bounds__(256,4)
__global__ void gemm_qkv(const us* __restrict__ A, const us* __restrict__ B,
                         const float* __restrict__ bias, us* __restrict__ C){
    __shared__ __attribute__((aligned(16))) us sA[128*64];
    __shared__ __attribute__((aligned(16))) us sB[128*64];
    int t = threadIdx.x;
    int id = blockIdx.x;                 // 3072
    int xcd = id & 7, s = id >> 3;
    int nt = s % 12, mt = xcd*32 + s/12;
    int lane = t&63, wave = t>>6, quad = lane>>4, l15 = lane&15;
    int wm = wave>>1, wn = wave&1;

    int l8 = lane>>3;
    int sw = ((lane&7) ^ l8)*8;
    const us* Ag = A + (size_t)(mt*128 + wave*32 + l8)*512 + sw;
    const us* Bg = B + (size_t)(nt*128 + wave*32 + l8)*512 + sw;
    us* sAw = &sA[(wave*32)*64];
    us* sBw = &sB[(wave*32)*64];

    f32x4 acc[4][4];
    #pragma unroll
    for(int i=0;i<4;i++)
        #pragma unroll
        for(int j=0;j<4;j++) acc[i][j] = (f32x4){0.f,0.f,0.f,0.f};

    // prologue: stage k0=0
    glds16(Ag,           sAw);
    glds16(Ag + 8*512,   sAw + 8*64);
    glds16(Ag + 16*512,  sAw + 16*64);
    glds16(Ag + 24*512,  sAw + 24*64);
    glds16(Bg,           sBw);
    glds16(Bg + 8*512,   sBw + 8*64);
    glds16(Bg + 16*512,  sBw + 16*64);
    glds16(Bg + 24*512,  sBw + 24*64);

    for(int k0=0; k0<512; k0+=64){
        __syncthreads();   // (a) drains vmcnt: stage(k0) visible; issued 1 MFMA-phase ago
        // ---- ks=0: read + MFMA ----
        {
            int kc = quad;
            s16x8 af[4], bfr[4];
            #pragma unroll
            for(int i=0;i<4;i++){
                int r = wm*64 + i*16 + l15;
                af[i] = *(const s16x8*)&sA[r*64 + ((kc ^ (r&7))<<3)];
            }
            #pragma unroll
            for(int j=0;j<4;j++){
                int r = wn*64 + j*16 + l15;
                bfr[j] = *(const s16x8*)&sB[r*64 + ((kc ^ (r&7))<<3)];
            }
            #pragma unroll
            for(int i=0;i<4;i++)
                #pragma unroll
                for(int j=0;j<4;j++)
                    acc[i][j] = __builtin_amdgcn_mfma_f32_16x16x32_bf16(bfr[j], af[i], acc[i][j], 0,0,0);
        }
        // ---- ks=1: read, then barrier, then stage(k+1), then MFMA ----
        s16x8 af1[4], bfr1[4];
        {
            int kc = 4 + quad;
            #pragma unroll
            for(int i=0;i<4;i++){
                int r = wm*64 + i*16 + l15;
                af1[i] = *(const s16x8*)&sA[r*64 + ((kc ^ (r&7))<<3)];
            }
            #pragma unroll
            for(int j=0;j<4;j++){
                int r = wn*64 + j*16 + l15;
                bfr1[j] = *(const s16x8*)&sB[r*64 + ((kc ^ (r&7))<<3)];
            }
        }
        if(k0 < 448){
            __syncthreads();             // (b) all waves done reading sA/sB
            int kn = k0 + 64;
            glds16(Ag + kn,           sAw);      // DMA overlaps ks1 MFMAs below
            glds16(Ag + 8*512 + kn,   sAw + 8*64);
            glds16(Ag + 16*512 + kn,  sAw + 16*64);
            glds16(Ag + 24*512 + kn,  sAw + 24*64);
            glds16(Bg + kn,           sBw);
            glds16(Bg + 8*512 + kn,   sBw + 8*64);
            glds16(Bg + 16*512 + kn,  sBw + 16*64);
            glds16(Bg + 24*512 + kn,  sBw + 24*64);
        }
        #pragma unroll
        for(int i=0;i<4;i++)
            #pragma unroll
            for(int j=0;j<4;j++)
                acc[i][j] = __builtin_amdgcn_mfma_f32_16x16x32_bf16(bfr1[j], af1[i], acc[i][j], 0,0,0);
    }

    // swapped layout: lane holds row = row0+i*16+l15, cols = col0+j*16+quad*4..+3
    int row0 = mt*128 + wm*64, col0 = nt*128 + wn*64;
    float4 bv[4];
    #pragma unroll
    for(int j=0;j<4;j++) bv[j] = *(const float4*)&bias[col0 + j*16 + quad*4];
    #pragma unroll
    for(int i=0;i<4;i++){
        size_t rb = (size_t)(row0 + i*16 + l15)*1536 + col0;
        #pragma unroll
        for(int j=0;j<4;j++){
            ushort4 o;
            o.x = f2bf(acc[i][j][0] + bv[j].x);
            o.y = f2bf(acc[i][j][1] + bv[j].y);
            o.z = f2bf(acc[i][j][2] + bv[j].z);
            o.w = f2bf(acc[i][j][3] + bv[j].w);
            *(ushort4*)&C[rb + j*16 + quad*4] = o;
        }
    }
}

// ---- scores: Spart[kb][head][d][e] = partial over 512 tokens (kb<8, 8 chunks) ----
__launch_bounds__(256,4)
__global__ void attn_scores_mfma(const us* __restrict__ qkv, float* __restrict__ Sp){
    __shared__ __attribute__((aligned(16))) us sQt[64*72];
    __shared__ __attribute__((aligned(16))) us sKt[64*72];
    int t = threadIdx.x;
    int kb = blockIdx.x, head = blockIdx.y;   // kb < 8
    int lane = t & 63, w = t >> 6;
    int quad = lane >> 4, l15 = lane & 15;
    int p = t & 31;
    int d0 = (t >> 5) * 8;

    f32x4 acc[4];
    #pragma unroll
    for(int j=0;j<4;j++) acc[j] = (f32x4){0.f,0.f,0.f,0.f};

    for(int chunk=0; chunk<8; chunk++){
        int r0 = head*512 + kb*64 + chunk*8;
        const us* g = qkv + (size_t)(r0 + (p>>2))*1536 + (2*(p&3))*64 + d0;
        union{uint4 v; us h[8];} q0, q1, k0, k1;
        q0.v = *(const uint4*)g;         q1.v = *(const uint4*)(g + 64);
        k0.v = *(const uint4*)(g + 512); k1.v = *(const uint4*)(g + 576);
        #pragma unroll
        for(int j=0;j<8;j++){
            *(unsigned*)&sQt[(d0+j)*72 + 2*p] = (unsigned)q0.h[j] | ((unsigned)q1.h[j]<<16);
            *(unsigned*)&sKt[(d0+j)*72 + 2*p] = (unsigned)k0.h[j] | ((unsigned)k1.h[j]<<16);
        }
        __syncthreads();
        int d = w*16 + l15;
        #pragma unroll
        for(int ks=0; ks<2; ks++){
            int tb = ks*4 + quad;
            s16x8 af = *(const s16x8*)&sQt[d*72 + tb*8];
            #pragma unroll
            for(int jt=0; jt<4; jt++){
                int e = jt*16 + l15;
                s16x8 bfv = *(const s16x8*)&sKt[e*72 + tb*8];
                acc[jt] = __builtin_amdgcn_mfma_f32_16x16x32_bf16(af, bfv, acc[jt], 0,0,0);
            }
        }
        __syncthreads();
    }

    float* S = Sp + (size_t)(kb*64 + head)*4096;
    #pragma unroll
    for(int jt=0; jt<4; jt++){
        int e = jt*16 + l15;
        #pragma unroll
        for(int r=0; r<4; r++){
            int d = w*16 + quad*4 + r;
            S[d*64 + e] = acc[jt][r];
        }
    }
}

// ---- fused softmax+fold (verified r4/r7/r8): 256 blocks (head,part). ----
__launch_bounds__(256,2)
__global__ void softfold(const float* __restrict__ Sp, const us* __restrict__ wpbf,
                         us* __restrict__ Mcat){
    __shared__ us sWt[64*72];   // W^T: sWt[e][d]
    int t = threadIdx.x;
    int head = blockIdx.x>>2, part = blockIdx.x&3;
    int b = head>>3, h = head&7;
    int lane = t&63, w = t>>6, quad = lane>>4, l15 = lane&15;

    int d = t>>2, e0 = (t&3)*16;
    float vv[16];
    #pragma unroll
    for(int j=0;j<16;j++) vv[j] = 0.f;
    for(int kb=0; kb<8; kb++){
        const float4* pp = (const float4*)&Sp[(size_t)(kb*64 + head)*4096 + d*64 + e0];
        #pragma unroll
        for(int q=0;q<4;q++){
            float4 g = pp[q];
            vv[4*q+0]+=g.x; vv[4*q+1]+=g.y; vv[4*q+2]+=g.z; vv[4*q+3]+=g.w;
        }
    }
    float m = -1e30f;
    #pragma unroll
    for(int j=0;j<16;j++){ vv[j] *= 0.125f; m = fmaxf(m, vv[j]); }
    m = fmaxf(m, __shfl_xor(m, 1));
    m = fmaxf(m, __shfl_xor(m, 2));
    float ssum = 0.f;
    #pragma unroll
    for(int j=0;j<16;j++){ vv[j] = __expf(vv[j]-m); ssum += vv[j]; }
    ssum += __shfl_xor(ssum, 1);
    ssum += __shfl_xor(ssum, 2);
    float inv = 1.f/ssum;
    #pragma unroll
    for(int j=0;j<16;j++) sWt[(e0+j)*72 + d] = f2bf(vv[j]*inv);
    __syncthreads();

    #pragma unroll
    for(int i=0;i<2;i++){
        int nO = part*128 + w*32 + i*16 + l15;
        s16x8 af0 = *(const s16x8*)&wpbf[(size_t)nO*512 + h*64 + quad*8];
        s16x8 af1 = *(const s16x8*)&wpbf[(size_t)nO*512 + h*64 + 32 + quad*8];
        #pragma unroll
        for(int j=0;j<4;j++){
            s16x8 bf0 = *(const s16x8*)&sWt[(j*16+l15)*72 + quad*8];
            s16x8 bf1 = *(const s16x8*)&sWt[(j*16+l15)*72 + 32 + quad*8];
            f32x4 acc = (f32x4){0.f,0.f,0.f,0.f};
            acc = __builtin_amdgcn_mfma_f32_16x16x32_bf16(af0, bf0, acc, 0,0,0);
            acc = __builtin_amdgcn_mfma_f32_16x16x32_bf16(af1, bf1, acc, 0,0,0);
            #pragma unroll
            for(int r=0;r<4;r++){
                int row = part*128 + w*32 + i*16 + quad*4 + r;
                Mcat[((size_t)(b*512 + row))*512 + h*64 + j*16 + l15] = f2bf(acc[r]);
            }
        }
    }
}

// ---- out_b = Vgather_b @ Mcat_b^T + wp_b. Swapped MFMA + float4 stores
// (verified r7/r8) + same T3-minimal stage-early reorder. ----
__launch_bounds__(256,4)
__global__ void gemm_vout(const us* __restrict__ qkv, const us* __restrict__ Mcat,
                          const float* __restrict__ bias, float* __restrict__ out){
    __shared__ __attribute__((aligned(16))) us sA[128*64];
    __shared__ __attribute__((aligned(16))) us sB[128*64];
    int t = threadIdx.x;
    int id = blockIdx.x;                 // 1024
    int xcd = id & 7, s = id >> 3;
    int nt = s & 3, mt = xcd*32 + (s>>2);
    int b = mt>>5, mr = mt&31;
    int lane = t&63, wave = t>>6, quad = lane>>4, l15 = lane&15;
    int wm = wave>>1, wn = wave&1;

    int l8 = lane>>3;
    int sw = ((lane&7) ^ l8)*8;
    const us* Abase = qkv + ((size_t)(8*b)*512 + mr*16 + wave*4)*1536 + 1024 + l8*64 + sw;
    const us* Bbase = Mcat + ((size_t)(b*512 + nt*128 + wave*32 + l8))*512 + sw;
    us* sAw = &sA[(wave*32)*64];
    us* sBw = &sB[(wave*32)*64];

    f32x4 acc[4][4];
    #pragma unroll
    for(int i=0;i<4;i++)
        #pragma unroll
        for(int j=0;j<4;j++) acc[i][j] = (f32x4){0.f,0.f,0.f,0.f};

    // prologue: stage h=0
    glds16(Abase,           sAw);
    glds16(Abase + 1536,    sAw + 8*64);
    glds16(Abase + 2*1536,  sAw + 16*64);
    glds16(Abase + 3*1536,  sAw + 24*64);
    glds16(Bbase,           sBw);
    glds16(Bbase + 8*512,   sBw + 8*64);
    glds16(Bbase + 16*512,  sBw + 16*64);
    glds16(Bbase + 24*512,  sBw + 24*64);

    for(int h=0; h<8; h++){
        __syncthreads();
        // ks=0 read + MFMA
        {
            int kc = quad;
            s16x8 af[4], bfr[4];
            #pragma unroll
            for(int i=0;i<4;i++){
                int r = wm*64 + i*16 + l15;
                af[i] = *(const s16x8*)&sA[r*64 + ((kc ^ (r&7))<<3)];
            }
            #pragma unroll
            for(int j=0;j<4;j++){
                int r = wn*64 + j*16 + l15;
                bfr[j] = *(const s16x8*)&sB[r*64 + ((kc ^ (r&7))<<3)];
            }
            #pragma unroll
            for(int i=0;i<4;i++)
                #pragma unroll
                for(int j=0;j<4;j++)
                    acc[i][j] = __builtin_amdgcn_mfma_f32_16x16x32_bf16(bfr[j], af[i], acc[i][j], 0,0,0);
        }
        // ks=1 read, barrier, stage(h+1), MFMA
        s16x8 af1[4], bfr1[4];
        {
            int kc = 4 + quad;
            #pragma unroll
            for(int i=0;i<4;i++){
                int r = wm*64 + i*16 + l15;
                af1[i] = *(const s16x8*)&sA[r*64 + ((kc ^ (r&7))<<3)];
            }
            #pragma unroll
            for(int j=0;j<4;j++){
                int r = wn*64 + j*16 + l15;
                bfr1[j] = *(const s16x8*)&sB[r*64 + ((kc ^ (r&7))<<3)];
            }
        }
        if(h < 7){
            __syncthreads();
            const us* Ah = Abase + (size_t)(h+1)*512*1536;
            const us* Bh = Bbase + (h+1)*64;
            glds16(Ah,           sAw);
            glds16(Ah + 1536,    sAw + 8*64);
            glds16(Ah + 2*1536,  sAw + 16*64);
            glds16(Ah + 3*1536,  sAw + 24*64);
            glds16(Bh,           sBw);
            glds16(Bh + 8*512,   sBw + 8*64);
            glds16(Bh + 16*512,  sBw + 16*64);
            glds16(Bh + 24*512,  sBw + 24*64);
        }
        #pragma unroll
        for(int i=0;i<4;i++)
            #pragma unroll
            for(int j=0;j<4;j++)
                acc[i][j] = __builtin_amdgcn_mfma_f32_16x16x32_bf16(bfr1[j], af1[i], acc[i][j], 0,0,0);
    }

    // swapped layout: lane holds row = row0+i*16+l15, cols = col0+j*16+quad*4..+3
    int row0 = b*4096 + mr*128 + wm*64;
    int col0 = nt*128 + wn*64;
    float4 bv[4];
    #pragma unroll
    for(int j=0;j<4;j++) bv[j] = *(const float4*)&bias[col0 + j*16 + quad*4];
    #pragma unroll
    for(int i=0;i<4;i++){
        size_t rb = (size_t)(row0 + i*16 + l15)*512 + col0;
        #pragma unroll
        for(int j=0;j<4;j++){
            float4 o;
            o.x = acc[i][j][0] + bv[j].x;
            o.y = acc[i][j][1] + bv[j].y;
            o.z = acc[i][j][2] + bv[j].z;
            o.w = acc[i][j][3] + bv[j].w;
            *(float4*)&out[rb + j*16 + quad*4] = o;
        }
    }
}

extern "C" void kernel_launch(void* const* d_in, const int* in_sizes, int n_in,
                              void* d_out, int out_size, void* d_ws, size_t ws_size,
                              hipStream_t stream){
    const float* x      = (const float*)d_in[0];
    const float* wqkv_w = (const float*)d_in[1];
    const float* wqkv_b = (const float*)d_in[2];
    const float* wp_w   = (const float*)d_in[3];
    const float* wp_b   = (const float*)d_in[4];

    char* ws = (char*)d_ws;
    us*    qkvbf  = (us*)(ws);                    // 96 MB
    us*    xbf    = (us*)(ws + 100663296);        // 32 MB
    float* Spart  = (float*)(ws + 134217728);     // 8 MB
    us*    Mcat   = (us*)(ws + 143130624);        // 4 MB
    us*    wqkvbf = (us*)(ws + 147324928);        // 1.5 MB
    us*    wpbf   = (us*)(ws + 148897792);        // 0.5 MB

    cast_all<<<17408,256,0,stream>>>(x, wqkv_w, wp_w, xbf, wqkvbf, wpbf);

    gemm_qkv<<<3072,256,0,stream>>>(xbf, wqkvbf, wqkv_b, qkvbf);

    attn_scores_mfma<<<dim3(8,64),256,0,stream>>>(qkvbf, Spart);
    softfold<<<256,256,0,stream>>>(Spart, wpbf, Mcat);

    gemm_vout<<<1024,256,0,stream>>>(qkvbf, Mcat, wp_b, (float*)d_out);
}